// Round 2
// baseline (18221.730 us; speedup 1.0000x reference)
//
#include <hip/hip_runtime.h>

#define T_STEPS 512
#define BATCH   64
#define HID     1024
#define G4      4096
#define IN      256
#define KTOT    1280          // HID + IN
#define CH      128
#define NCHH    8             // h chunks (1024/128)
#define NCHX    2             // x chunks (256/128)
#define LDS_FLOATS 37120      // 20480 w + 8192 bufA + 8192 bufB + 256 hfc
#define LDS_BYTES  (LDS_FLOATS * 4)

// ---------------------------------------------------------------------------
// out init (b_fc) + flag clear.  grid 128 x 256.
// ---------------------------------------------------------------------------
__global__ __launch_bounds__(256) void init_k(
    float* __restrict__ out, int* __restrict__ flags, const float* __restrict__ bfc)
{
    int i = blockIdx.x * 256 + threadIdx.x;
    if (i < BATCH * T_STEPS) out[i] = bfc[0];
    if (i < 256) flags[i] = 0;
}

// ---------------------------------------------------------------------------
// x[b][t][i] -> xT[t][i][b].  grid (IN/64, 1, T), block 256.
// ---------------------------------------------------------------------------
__global__ __launch_bounds__(256) void transpose_x_k(
    const float* __restrict__ x, float* __restrict__ xT)
{
    __shared__ float tile[64][65];
    const int t = blockIdx.z, c0 = blockIdx.x * 64;
    const int tr = threadIdx.x >> 6, tc = threadIdx.x & 63;
#pragma unroll
    for (int p = 0; p < 16; ++p) {
        int b = p * 4 + tr;
        tile[b][tc] = x[((size_t)b * T_STEPS + t) * IN + c0 + tc];
    }
    __syncthreads();
#pragma unroll
    for (int p = 0; p < 16; ++p) {
        int il = p * 4 + tr;
        xT[(size_t)t * (IN * BATCH) + (size_t)(c0 + il) * BATCH + tc] = tile[tc][il];
    }
}

// ---------------------------------------------------------------------------
// Persistent fused LSTM. grid 256 (1 WG/CU, forced by 148KB LDS), block 512.
// WG w owns hidden units u0..u0+3 (16 gate rows). Weight slice [1280][16]
// lives in LDS for the whole kernel. Per step: stage K-chunks of
// v=[h_{t-1};x_t] (double-buffered, 1 barrier/chunk), FMA into acc[16] f4,
// shuffle-reduce, gate math, write h to global dbuf, atomicAdd FC into out.
// ---------------------------------------------------------------------------
__global__ __launch_bounds__(512) void lstm_seq(
    const float* __restrict__ Whh, const float* __restrict__ Wih,
    const float* __restrict__ bih, const float* __restrict__ bhh,
    const float* __restrict__ Wfc, const float* __restrict__ xT,
    float* __restrict__ h_buf,    // [2][HID][BATCH]
    float* __restrict__ out,      // [BATCH][T]
    int* __restrict__ flags)      // [256]
{
    extern __shared__ float smem[];
    float* w_lds = smem;             // [1280][16]
    float* bufA  = smem + 20480;     // [128][64]
    float* bufB  = smem + 28672;     // [128][64]
    float* red   = bufA;             // alias: [8 wv][16 r][64 b]
    float* hfc   = smem + 36864;     // [4][64]

    const int tid  = threadIdx.x;
    const int wg   = blockIdx.x;
    const int u0   = wg * 4;
    const int lane = tid & 63;
    const int wv   = tid >> 6;            // wave 0..7
    const int q    = lane & 15;
    const int ks   = lane >> 4;           // 0..3 (k sub-slot, consecutive k)
    const int b0   = q * 4;
    const int hoff = (wv * 16 + ks) * 64 + b0;  // + ii*256
    const int woff = (wv * 16 + ks) * 16;       // + koff*16 + ii*64

    // ---- one-time: weight slice -> LDS (coalesced along k) ----
    {
        const int rloc = tid >> 5;        // 0..15 = gi*4+ui
        const int l32  = tid & 31;
        const int gi = rloc >> 2, ui = rloc & 3;
        const int grow = gi * HID + u0 + ui;
        for (int kb = 0; kb < KTOT; kb += 128) {
            int k = kb + l32 * 4;
            float4 v;
            if (k < HID) v = *(const float4*)&Whh[(size_t)grow * HID + k];
            else         v = *(const float4*)&Wih[(size_t)grow * IN + (k - HID)];
            w_lds[(k + 0) * 16 + rloc] = v.x;
            w_lds[(k + 1) * 16 + rloc] = v.y;
            w_lds[(k + 2) * 16 + rloc] = v.z;
            w_lds[(k + 3) * 16 + rloc] = v.w;
        }
    }

    // per-thread epilogue constants ((tid>>6)&3 keeps waves 4..7 in-bounds)
    const int ui_ep = (tid >> 6) & 3;
    const int b_ep  = tid & 63;
    float bias_r[4], wfc_r[4];
#pragma unroll
    for (int gi = 0; gi < 4; ++gi)
        bias_r[gi] = bih[gi * HID + u0 + ui_ep] + bhh[gi * HID + u0 + ui_ep];
#pragma unroll
    for (int ui = 0; ui < 4; ++ui) wfc_r[ui] = Wfc[u0 + ui];

    float c_state = 0.f;
    __syncthreads();   // w_lds ready

    for (int t = 0; t < T_STEPS; ++t) {
        // ---- wait: all WGs finished step t-1 (wave 0 polls 256 flags) ----
        if (t > 0 && wv == 0) {
            for (;;) {
                int m0 = __hip_atomic_load(flags + lane * 4 + 0, __ATOMIC_RELAXED, __HIP_MEMORY_SCOPE_AGENT);
                int m1 = __hip_atomic_load(flags + lane * 4 + 1, __ATOMIC_RELAXED, __HIP_MEMORY_SCOPE_AGENT);
                int m2 = __hip_atomic_load(flags + lane * 4 + 2, __ATOMIC_RELAXED, __HIP_MEMORY_SCOPE_AGENT);
                int m3 = __hip_atomic_load(flags + lane * 4 + 3, __ATOMIC_RELAXED, __HIP_MEMORY_SCOPE_AGENT);
                if (__all(min(min(m0, m1), min(m2, m3)) >= t)) break;
                __builtin_amdgcn_s_sleep(2);
            }
            __threadfence();   // acquire: refuse stale cached h
        }
        __syncthreads();

        const float* hprev = h_buf + (size_t)((t - 1) & 1) * (HID * BATCH);
        const float* xcur  = xT + (size_t)t * (IN * BATCH);
        const int nch   = (t > 0) ? (NCHH + NCHX) : NCHX;
        const int cbase = (t > 0) ? 0 : NCHH;     // t=0: x chunks only (h=-0)

        float4 acc[16];
#pragma unroll
        for (int r = 0; r < 16; ++r) { acc[r].x = acc[r].y = acc[r].z = acc[r].w = 0.f; }

        float4 sh[4];
        // prologue: stage first chunk into bufA
        {
            const float* s = (cbase < NCHH) ? (hprev + cbase * CH * BATCH)
                                            : (xcur + (cbase - NCHH) * CH * BATCH);
#pragma unroll
            for (int i2 = 0; i2 < 4; ++i2) sh[i2] = *(const float4*)&s[(tid + i2 * 512) * 4];
#pragma unroll
            for (int i2 = 0; i2 < 4; ++i2) *(float4*)&bufA[(tid + i2 * 512) * 4] = sh[i2];
        }
        __syncthreads();

        float* cb = bufA; float* nb = bufB;
        for (int j = 0; j < nch; ++j) {
            const int cid = cbase + j;
            if (j + 1 < nch) {   // prefetch next chunk into regs
                const int nid = cid + 1;
                const float* s = (nid < NCHH) ? (hprev + nid * CH * BATCH)
                                              : (xcur + (nid - NCHH) * CH * BATCH);
#pragma unroll
                for (int i2 = 0; i2 < 4; ++i2) sh[i2] = *(const float4*)&s[(tid + i2 * 512) * 4];
            }
            const float* wb = w_lds + cid * CH * 16 + woff;
            const float* hb = cb + hoff;
#pragma unroll
            for (int ii = 0; ii < 4; ++ii) {
                float4 hv = *(const float4*)&hb[ii * 256];
                float4 w0 = *(const float4*)&wb[ii * 64 + 0];
                float4 w1 = *(const float4*)&wb[ii * 64 + 4];
                float4 w2 = *(const float4*)&wb[ii * 64 + 8];
                float4 w3 = *(const float4*)&wb[ii * 64 + 12];
#define FMA_ROW(A, WS) { A.x = fmaf(WS, hv.x, A.x); A.y = fmaf(WS, hv.y, A.y); \
                         A.z = fmaf(WS, hv.z, A.z); A.w = fmaf(WS, hv.w, A.w); }
                FMA_ROW(acc[0],  w0.x) FMA_ROW(acc[1],  w0.y) FMA_ROW(acc[2],  w0.z) FMA_ROW(acc[3],  w0.w)
                FMA_ROW(acc[4],  w1.x) FMA_ROW(acc[5],  w1.y) FMA_ROW(acc[6],  w1.z) FMA_ROW(acc[7],  w1.w)
                FMA_ROW(acc[8],  w2.x) FMA_ROW(acc[9],  w2.y) FMA_ROW(acc[10], w2.z) FMA_ROW(acc[11], w2.w)
                FMA_ROW(acc[12], w3.x) FMA_ROW(acc[13], w3.y) FMA_ROW(acc[14], w3.z) FMA_ROW(acc[15], w3.w)
#undef FMA_ROW
            }
            if (j + 1 < nch) {   // write prefetched chunk into the other buffer
#pragma unroll
                for (int i2 = 0; i2 < 4; ++i2) *(float4*)&nb[(tid + i2 * 512) * 4] = sh[i2];
            }
            __syncthreads();
            float* tmp = cb; cb = nb; nb = tmp;
        }

        // ---- reduce ks groups (lane bits 4,5), park partials in LDS ----
#pragma unroll
        for (int r = 0; r < 16; ++r) {
            acc[r].x += __shfl_xor(acc[r].x, 16); acc[r].y += __shfl_xor(acc[r].y, 16);
            acc[r].z += __shfl_xor(acc[r].z, 16); acc[r].w += __shfl_xor(acc[r].w, 16);
            acc[r].x += __shfl_xor(acc[r].x, 32); acc[r].y += __shfl_xor(acc[r].y, 32);
            acc[r].z += __shfl_xor(acc[r].z, 32); acc[r].w += __shfl_xor(acc[r].w, 32);
        }
        if (ks == 0) {
#pragma unroll
            for (int r = 0; r < 16; ++r)
                *(float4*)&red[wv * 1024 + r * 64 + b0] = acc[r];
        }
        __syncthreads();

        // ---- epilogue: gates -> c,h; h to global dbuf; FC partial ----
        if (tid < 256) {
            float pre[4];
#pragma unroll
            for (int gi = 0; gi < 4; ++gi) {
                float s = bias_r[gi];
#pragma unroll
                for (int w8 = 0; w8 < 8; ++w8)
                    s += red[w8 * 1024 + (gi * 4 + ui_ep) * 64 + b_ep];
                pre[gi] = s;
            }
            float ig = 1.f / (1.f + expf(-pre[0]));
            float fg = 1.f / (1.f + expf(-pre[1]));
            float gg = tanhf(pre[2]);
            float og = 1.f / (1.f + expf(-pre[3]));
            c_state = fg * c_state + ig * gg;
            float hv = og * tanhf(c_state);
            h_buf[(size_t)(t & 1) * (HID * BATCH) + (u0 + ui_ep) * BATCH + b_ep] = hv;
            hfc[ui_ep * 64 + b_ep] = hv * wfc_r[ui_ep];
        }
        __syncthreads();
        if (tid < 64) {
            float fc = hfc[tid] + hfc[64 + tid] + hfc[128 + tid] + hfc[192 + tid];
            atomicAdd(&out[(size_t)tid * T_STEPS + t], fc);
        }
        if (tid == 0) {
            __threadfence();   // flush h stores to device-coherent point
            __hip_atomic_store(flags + wg, t + 1, __ATOMIC_RELEASE, __HIP_MEMORY_SCOPE_AGENT);
        }
        // no extra barrier: next iteration's prologue writes bufA only after
        // the post-spin __syncthreads; red reads finished before the sync above.
    }
}

// ---------------------------------------------------------------------------
extern "C" void kernel_launch(void* const* d_in, const int* in_sizes, int n_in,
                              void* d_out, int out_size, void* d_ws, size_t ws_size,
                              hipStream_t stream)
{
    const float* x   = (const float*)d_in[0];
    const float* Wih = (const float*)d_in[1];
    const float* Whh = (const float*)d_in[2];
    const float* bih = (const float*)d_in[3];
    const float* bhh = (const float*)d_in[4];
    const float* Wfc = (const float*)d_in[5];
    const float* bfc = (const float*)d_in[6];
    float* out = (float*)d_out;

    float* ws    = (float*)d_ws;
    float* xT    = ws;                                        // 512*256*64  = 8,388,608 f
    float* h_buf = xT + (size_t)T_STEPS * IN * BATCH;         // 2*1024*64   =   131,072 f
    int*   flags = (int*)(h_buf + 2 * HID * BATCH);           // 256 ints    (~34 MB total)

    // allow >64KB dynamic LDS for the persistent kernel (ignore errors)
    (void)hipFuncSetAttribute((const void*)lstm_seq,
                              hipFuncAttributeMaxDynamicSharedMemorySize, LDS_BYTES);

    init_k<<<dim3((BATCH * T_STEPS + 255) / 256), dim3(256), 0, stream>>>(out, flags, bfc);
    transpose_x_k<<<dim3(IN / 64, 1, T_STEPS), dim3(256), 0, stream>>>(x, xT);
    lstm_seq<<<dim3(256), dim3(512), LDS_BYTES, stream>>>(
        Whh, Wih, bih, bhh, Wfc, xT, h_buf, out, flags);
}

// Round 4
// 6678.860 us; speedup vs baseline: 2.7283x; 2.7283x over previous
//
#include <hip/hip_runtime.h>

#define T_STEPS 512
#define BATCH   64
#define HID     1024
#define G4      4096
#define IN      256
#define KTOT    1280          // HID + IN
#define LDS_FLOATS 28928      // 20480 w + 8192 red + 256 hfc
#define LDS_BYTES  (LDS_FLOATS * 4)

typedef float f32x4 __attribute__((ext_vector_type(4)));

// ---------------------------------------------------------------------------
// out init (b_fc) + flag clear.  grid 128 x 256.
// ---------------------------------------------------------------------------
__global__ __launch_bounds__(256) void init_k(
    float* __restrict__ out, int* __restrict__ flags, const float* __restrict__ bfc)
{
    int i = blockIdx.x * 256 + threadIdx.x;
    if (i < BATCH * T_STEPS) out[i] = bfc[0];
    if (i < 256) flags[i] = 0;
}

// ---------------------------------------------------------------------------
// x[b][t][i] -> xT[t][i][b].  grid (IN/64, 1, T), block 256.
// ---------------------------------------------------------------------------
__global__ __launch_bounds__(256) void transpose_x_k(
    const float* __restrict__ x, float* __restrict__ xT)
{
    __shared__ float tile[64][65];
    const int t = blockIdx.z, c0 = blockIdx.x * 64;
    const int tr = threadIdx.x >> 6, tc = threadIdx.x & 63;
#pragma unroll
    for (int p = 0; p < 16; ++p) {
        int b = p * 4 + tr;
        tile[b][tc] = x[((size_t)b * T_STEPS + t) * IN + c0 + tc];
    }
    __syncthreads();
#pragma unroll
    for (int p = 0; p < 16; ++p) {
        int il = p * 4 + tr;
        xT[(size_t)t * (IN * BATCH) + (size_t)(c0 + il) * BATCH + tc] = tile[tc][il];
    }
}

// ---------------------------------------------------------------------------
// Coherent (L1+L2-bypass) 4x16B load issue: dest regs valid only AFTER a
// subsequent s_waitcnt vmcnt(0) + sched_barrier(0)  (guide rule #18).
// ---------------------------------------------------------------------------
__device__ __forceinline__ void issue_coh(const float* p,
                                          f32x4& r0, f32x4& r1, f32x4& r2, f32x4& r3)
{
    asm volatile(
        "global_load_dwordx4 %0, %4, off sc0 sc1\n\t"
        "global_load_dwordx4 %1, %4, off offset:1024 sc0 sc1\n\t"
        "global_load_dwordx4 %2, %4, off offset:2048 sc0 sc1\n\t"
        "global_load_dwordx4 %3, %4, off offset:3072 sc0 sc1"
        : "=&v"(r0), "=&v"(r1), "=&v"(r2), "=&v"(r3)
        : "v"(p));
}

// 64 FMAs for one (chunk, ii-quad): va[4] k-rows x 16 gate rows x 4 batch
__device__ __forceinline__ void fma_chunk(const f32x4* va, const float* wb, f32x4* acc)
{
#pragma unroll
    for (int ii = 0; ii < 4; ++ii) {
        const f32x4 hv = va[ii];
        const f32x4 w0 = *(const f32x4*)(wb + ii * 64 + 0);
        const f32x4 w1 = *(const f32x4*)(wb + ii * 64 + 4);
        const f32x4 w2 = *(const f32x4*)(wb + ii * 64 + 8);
        const f32x4 w3 = *(const f32x4*)(wb + ii * 64 + 12);
        acc[0]  += w0.x * hv; acc[1]  += w0.y * hv; acc[2]  += w0.z * hv; acc[3]  += w0.w * hv;
        acc[4]  += w1.x * hv; acc[5]  += w1.y * hv; acc[6]  += w1.z * hv; acc[7]  += w1.w * hv;
        acc[8]  += w2.x * hv; acc[9]  += w2.y * hv; acc[10] += w2.z * hv; acc[11] += w2.w * hv;
        acc[12] += w3.x * hv; acc[13] += w3.y * hv; acc[14] += w3.z * hv; acc[15] += w3.w * hv;
    }
}

// ---------------------------------------------------------------------------
// Persistent fused LSTM. grid 256 (1 WG/CU via 113KB LDS), block 512.
// WG owns 4 hidden units (16 gate rows); weights [1280][16] persistent in LDS.
// Per step: x-part FMA (pre-barrier overlap) -> spin-wait -> h-part FMA with
// register-double-buffered coherent loads (NO LDS staging, NO fences) ->
// shuffle+LDS reduce -> gates -> h store (agent-scope) -> FC atomicAdd.
// ---------------------------------------------------------------------------
__global__ __launch_bounds__(512) void lstm_seq(
    const float* __restrict__ Whh, const float* __restrict__ Wih,
    const float* __restrict__ bih, const float* __restrict__ bhh,
    const float* __restrict__ Wfc, const float* __restrict__ xT,
    float* __restrict__ h_buf,    // [2][HID][BATCH]
    float* __restrict__ out,      // [BATCH][T]
    int* __restrict__ flags)      // [256]
{
    extern __shared__ float smem[];
    float* w_lds = smem;             // [1280][16]
    float* red   = smem + 20480;     // [8 wv][16 r][64 b]
    float* hfc   = smem + 28672;     // [4][64]

    const int tid  = threadIdx.x;
    const int wg   = blockIdx.x;
    const int u0   = wg * 4;
    const int lane = tid & 63;
    const int wv   = tid >> 6;            // wave 0..7
    const int q    = lane & 15;
    const int ks   = lane >> 4;           // 0..3
    const int b0   = q * 4;
    const int roff = (wv * 16 + ks);      // k-row offset within a 128-chunk
    const int woff = roff * 16;

    // ---- one-time: weight slice -> LDS (coalesced along k) ----
    {
        const int rloc = tid >> 5;        // 0..15 = gi*4+ui
        const int l32  = tid & 31;
        const int gi = rloc >> 2, ui = rloc & 3;
        const int grow = gi * HID + u0 + ui;
        for (int kb = 0; kb < KTOT; kb += 128) {
            int k = kb + l32 * 4;
            float4 v;
            if (k < HID) v = *(const float4*)&Whh[(size_t)grow * HID + k];
            else         v = *(const float4*)&Wih[(size_t)grow * IN + (k - HID)];
            w_lds[(k + 0) * 16 + rloc] = v.x;
            w_lds[(k + 1) * 16 + rloc] = v.y;
            w_lds[(k + 2) * 16 + rloc] = v.z;
            w_lds[(k + 3) * 16 + rloc] = v.w;
        }
    }

    const int ui_ep = (tid >> 6) & 3;
    const int b_ep  = tid & 63;
    float bias_r[4], wfc_r[4];
#pragma unroll
    for (int gi = 0; gi < 4; ++gi)
        bias_r[gi] = bih[gi * HID + u0 + ui_ep] + bhh[gi * HID + u0 + ui_ep];
#pragma unroll
    for (int ui = 0; ui < 4; ++ui) wfc_r[ui] = Wfc[u0 + ui];

    float c_state = 0.f;
    __syncthreads();   // w_lds ready

    for (int t = 0; t < T_STEPS; ++t) {
        f32x4 acc[16];
#pragma unroll
        for (int r = 0; r < 16; ++r) acc[r] = (f32x4)0.f;

        // ---- x part first (independent of h): chunks cid 8,9 ----
        const float* xb = xT + (size_t)t * (IN * BATCH) + roff * 64 + b0;
#pragma unroll
        for (int j = 0; j < 2; ++j) {
            f32x4 xv[4];
#pragma unroll
            for (int ii = 0; ii < 4; ++ii)
                xv[ii] = *(const f32x4*)(xb + j * 8192 + ii * 256);
            fma_chunk(xv, w_lds + (8 + j) * 2048 + woff, acc);
        }

        // ---- h part: wait for all WGs' step t-1, then coherent-load h ----
        if (t > 0) {
            if (wv == 0) {
                for (;;) {
                    int m0 = __hip_atomic_load(flags + lane * 4 + 0, __ATOMIC_RELAXED, __HIP_MEMORY_SCOPE_AGENT);
                    int m1 = __hip_atomic_load(flags + lane * 4 + 1, __ATOMIC_RELAXED, __HIP_MEMORY_SCOPE_AGENT);
                    int m2 = __hip_atomic_load(flags + lane * 4 + 2, __ATOMIC_RELAXED, __HIP_MEMORY_SCOPE_AGENT);
                    int m3 = __hip_atomic_load(flags + lane * 4 + 3, __ATOMIC_RELAXED, __HIP_MEMORY_SCOPE_AGENT);
                    if (__all(min(min(m0, m1), min(m2, m3)) >= t)) break;
                    __builtin_amdgcn_s_sleep(2);
                }
                // no fence needed: h loads below bypass L1/L2 (sc0 sc1)
            }
            __syncthreads();

            const float* hb = h_buf + (size_t)((t - 1) & 1) * (HID * BATCH) + roff * 64 + b0;
            f32x4 va[2][4];
            issue_coh(hb, va[0][0], va[0][1], va[0][2], va[0][3]);
#pragma unroll
            for (int j = 0; j < 8; ++j) {
                asm volatile("s_waitcnt vmcnt(0)" ::: "memory");
                if (j < 7)
                    issue_coh(hb + (j + 1) * 8192,
                              va[(j + 1) & 1][0], va[(j + 1) & 1][1],
                              va[(j + 1) & 1][2], va[(j + 1) & 1][3]);
                __builtin_amdgcn_sched_barrier(0);
                fma_chunk(va[j & 1], w_lds + j * 2048 + woff, acc);
            }
        }

        // ---- reduce ks groups (lane bits 4,5), park partials in LDS ----
#pragma unroll
        for (int r = 0; r < 16; ++r) {
            acc[r].x += __shfl_xor(acc[r].x, 16); acc[r].y += __shfl_xor(acc[r].y, 16);
            acc[r].z += __shfl_xor(acc[r].z, 16); acc[r].w += __shfl_xor(acc[r].w, 16);
            acc[r].x += __shfl_xor(acc[r].x, 32); acc[r].y += __shfl_xor(acc[r].y, 32);
            acc[r].z += __shfl_xor(acc[r].z, 32); acc[r].w += __shfl_xor(acc[r].w, 32);
        }
        if (ks == 0) {
#pragma unroll
            for (int r = 0; r < 16; ++r)
                *(f32x4*)&red[wv * 1024 + r * 64 + b0] = acc[r];
        }
        __syncthreads();

        // ---- epilogue: gates -> c,h; h agent-scope store; FC partial ----
        if (tid < 256) {
            float pre[4];
#pragma unroll
            for (int gi = 0; gi < 4; ++gi) {
                float s = bias_r[gi];
#pragma unroll
                for (int w8 = 0; w8 < 8; ++w8)
                    s += red[w8 * 1024 + (gi * 4 + ui_ep) * 64 + b_ep];
                pre[gi] = s;
            }
            float ig = 1.f / (1.f + expf(-pre[0]));
            float fg = 1.f / (1.f + expf(-pre[1]));
            float gg = tanhf(pre[2]);
            float og = 1.f / (1.f + expf(-pre[3]));
            c_state = fg * c_state + ig * gg;
            float hv = og * tanhf(c_state);
            __hip_atomic_store(&h_buf[(size_t)(t & 1) * (HID * BATCH) + (u0 + ui_ep) * BATCH + b_ep],
                               hv, __ATOMIC_RELAXED, __HIP_MEMORY_SCOPE_AGENT);
            hfc[ui_ep * 64 + b_ep] = hv * wfc_r[ui_ep];
        }
        // explicit release: every wave drains its own h stores before the
        // barrier, so after it the WG's h is agent-visible (don't rely on
        // barrier lowering details).
        asm volatile("s_waitcnt vmcnt(0)" ::: "memory");
        __syncthreads();
        if (tid < 64) {
            float fc = hfc[tid] + hfc[64 + tid] + hfc[128 + tid] + hfc[192 + tid];
            atomicAdd(&out[(size_t)tid * T_STEPS + t], fc);
        }
        if (tid == 0) {
            __hip_atomic_store(flags + wg, t + 1, __ATOMIC_RELAXED, __HIP_MEMORY_SCOPE_AGENT);
        }
    }
}

// ---------------------------------------------------------------------------
extern "C" void kernel_launch(void* const* d_in, const int* in_sizes, int n_in,
                              void* d_out, int out_size, void* d_ws, size_t ws_size,
                              hipStream_t stream)
{
    const float* x   = (const float*)d_in[0];
    const float* Wih = (const float*)d_in[1];
    const float* Whh = (const float*)d_in[2];
    const float* bih = (const float*)d_in[3];
    const float* bhh = (const float*)d_in[4];
    const float* Wfc = (const float*)d_in[5];
    const float* bfc = (const float*)d_in[6];
    float* out = (float*)d_out;

    float* ws    = (float*)d_ws;
    float* xT    = ws;                                        // 512*256*64
    float* h_buf = xT + (size_t)T_STEPS * IN * BATCH;         // 2*1024*64
    int*   flags = (int*)(h_buf + 2 * HID * BATCH);           // 256 ints

    (void)hipFuncSetAttribute((const void*)lstm_seq,
                              hipFuncAttributeMaxDynamicSharedMemorySize, LDS_BYTES);

    init_k<<<dim3((BATCH * T_STEPS + 255) / 256), dim3(256), 0, stream>>>(out, flags, bfc);
    transpose_x_k<<<dim3(IN / 64, 1, T_STEPS), dim3(256), 0, stream>>>(x, xT);
    lstm_seq<<<dim3(256), dim3(512), LDS_BYTES, stream>>>(
        Whh, Wih, bih, bhh, Wfc, xT, h_buf, out, flags);
}